// Round 1
// baseline (819.568 us; speedup 1.0000x reference)
//
#include <hip/hip_runtime.h>

// URPE: out[b,h,i,j] = attn[b,h,i,j] * toe(h, i, j)
// toe(h,i,j) = (j >= i) ? w[h, L + j - i] : w[h, i - j]
// B=2, H=16, L=2048 -> attn is 512 MiB fp32; pure memory-bound multiply.

#define URPE_B 2
#define URPE_H 16
#define URPE_L 2048

__global__ __launch_bounds__(512) void urpe_mul_kernel(
    const float* __restrict__ attn,
    const float* __restrict__ w,
    float* __restrict__ out)
{
    const int i  = blockIdx.x;            // query position (row), [0, L)
    const int bh = blockIdx.y;            // b*H + h
    const int h  = bh & (URPE_H - 1);

    const float* __restrict__ wh = w + (size_t)h * (2 * URPE_L);
    const size_t base = ((size_t)bh * URPE_L + (size_t)i) * URPE_L;

    const int j0 = threadIdx.x << 2;      // 512 threads * 4 floats = 2048 = L

    float4 a = *reinterpret_cast<const float4*>(attn + base + j0);

    int j = j0;
    float w0 = (j >= i) ? wh[URPE_L + j - i] : wh[i - j]; ++j;
    float w1 = (j >= i) ? wh[URPE_L + j - i] : wh[i - j]; ++j;
    float w2 = (j >= i) ? wh[URPE_L + j - i] : wh[i - j]; ++j;
    float w3 = (j >= i) ? wh[URPE_L + j - i] : wh[i - j];

    float4 o;
    o.x = a.x * w0;
    o.y = a.y * w1;
    o.z = a.z * w2;
    o.w = a.w * w3;

    *reinterpret_cast<float4*>(out + base + j0) = o;
}

extern "C" void kernel_launch(void* const* d_in, const int* in_sizes, int n_in,
                              void* d_out, int out_size, void* d_ws, size_t ws_size,
                              hipStream_t stream)
{
    const float* attn = (const float*)d_in[0];   // (B, H, L, L) fp32
    const float* w    = (const float*)d_in[1];   // (H, 2L) fp32
    float* out        = (float*)d_out;           // (B, H, L, L) fp32

    dim3 grid(URPE_L, URPE_B * URPE_H);
    urpe_mul_kernel<<<grid, 512, 0, stream>>>(attn, w, out);
}